// Round 7
// baseline (430.062 us; speedup 1.0000x reference)
//
#include <hip/hip_runtime.h>
#include <hip/hip_bf16.h>
#include <math.h>

#define B_  2
#define L_  2048
#define D_  256
#define H_  8
#define HD_ 32
#define F_  1024
#define LY_ 4
#define M_  (B_*L_)

typedef __attribute__((ext_vector_type(8))) short bf16x8;   // 8 bf16 in 4 VGPRs
typedef __attribute__((ext_vector_type(4))) float f32x4;

static __device__ __forceinline__ short f2bf(float f) {
    return __builtin_bit_cast(short, __float2bfloat16(f));
}

static __device__ __forceinline__ void gload_lds16(const ushort* g, ushort* l) {
    __builtin_amdgcn_global_load_lds(
        (const __attribute__((address_space(1))) void*)g,
        (__attribute__((address_space(3))) void*)l, 16, 0, 0);
}

// ---------------------------------------------------------------------------
// Weight transpose + fp32->bf16:  W[K][N] -> Wt[N][K] bf16  (unchanged)
// ---------------------------------------------------------------------------
__global__ __launch_bounds__(256) void transpose_weights(
    const float* __restrict__ Win, const float* __restrict__ Wq,
    const float* __restrict__ Wk,  const float* __restrict__ Wv,
    const float* __restrict__ Wo,  const float* __restrict__ W1,
    const float* __restrict__ W2,  const float* __restrict__ Wout,
    ushort* __restrict__ T)
{
    const int bid = blockIdx.x;
    const float* src; ushort* dst; int K, N, tt;
    if (bid < 64)        { src = Win; dst = T; K = 256; N = 256; tt = bid; }
    else if (bid < 1088) {
        int i = bid - 64; int which = i >> 8; int l = (i >> 6) & 3; tt = i & 63;
        K = 256; N = 256;
        const float* s4[4] = {Wq, Wk, Wv, Wo};
        src = s4[which] + l * 65536;
        dst = T + 65536 * (1 + which * 4 + l);
    } else if (bid < 2112) {
        int i = bid - 1088; int l = i >> 8; tt = i & 255; K = 256; N = 1024;
        src = W1 + l * 262144; dst = T + 65536 * 17 + l * 262144;
    } else if (bid < 3136) {
        int i = bid - 2112; int l = i >> 8; tt = i & 255; K = 1024; N = 256;
        src = W2 + l * 262144; dst = T + 65536 * 17 + 1048576 + l * 262144;
    } else {
        src = Wout; dst = T + 65536 * 17 + 2097152; K = 256; N = 256; tt = bid - 3136;
    }
    const int ntn = N >> 5;
    const int tk = tt / ntn, tn = tt % ntn;
    __shared__ float ld[32][33];
    const int t = threadIdx.x;
    const int r = t >> 3, c4 = (t & 7) * 4;
    float4 v = *reinterpret_cast<const float4*>(&src[(size_t)(tk * 32 + r) * N + tn * 32 + c4]);
    ld[r][c4 + 0] = v.x; ld[r][c4 + 1] = v.y; ld[r][c4 + 2] = v.z; ld[r][c4 + 3] = v.w;
    __syncthreads();
    short4 o;
    o.x = f2bf(ld[c4 + 0][r]);
    o.y = f2bf(ld[c4 + 1][r]);
    o.z = f2bf(ld[c4 + 2][r]);
    o.w = f2bf(ld[c4 + 3][r]);
    *reinterpret_cast<short4*>(&dst[(size_t)(tn * 32 + r) * K + tk * 32 + c4]) = o;
}

// ---------------------------------------------------------------------------
// Fused LN(+convert) GEMM core, K=256 only.
// Prologue: load 64 fp32 rows of Hin, LN per row (4-lane shuffle stats),
// write normalized bf16 A-tile to LDS [64][264] (row stride 132 words ->
// 2 lanes/bank on b128 reads = free). K-loop streams W via async
// global_load_lds, double-buffered, one barrier per BK=64.
// LNMODE: 0 = convert only, 1 = LayerNorm.
// ---------------------------------------------------------------------------
template<int LNMODE>
__device__ __forceinline__ void gemm_core_ln(
    const float* __restrict__ Hin, const float* __restrict__ lng,
    const float* __restrict__ lnb, const ushort* __restrict__ Wt,
    int row0, int col0, ushort* sLN, ushort* sW, f32x4 acc[2][2])
{
    const int tid  = threadIdx.x;
    const int lane = tid & 63;
    const int wid  = tid >> 6;
    const int wr = wid >> 1, wc = wid & 1;
    const int g = lane >> 4, nn = lane & 15;

    // --- issue W DMA for k0=0 (lands while LN prologue runs)
    const int r0 = tid >> 3;
    const int sx = ((tid & 7) ^ (r0 & 7)) << 3;
    const ushort* Wp = &Wt[(size_t)(col0 + r0) * 256 + sx];
    ushort* ldsW = sW + wid * 512;
    gload_lds16(Wp,            ldsW);
    gload_lds16(Wp + 32 * 256, ldsW + 2048);

    // --- LN prologue: thread covers row (tid>>2), quarter (tid&3)
    {
        const int prow = tid >> 2;
        const int pq   = tid & 3;
        const float* hp = &Hin[(size_t)(row0 + prow) * D_ + pq * 64];
        float4 v[16];
#pragma unroll
        for (int j = 0; j < 16; ++j) v[j] = reinterpret_cast<const float4*>(hp)[j];
        float mean = 0.f, rstd = 0.f;
        if (LNMODE) {
            float s = 0.f, s2 = 0.f;
#pragma unroll
            for (int j = 0; j < 16; ++j) {
                s  += v[j].x + v[j].y + v[j].z + v[j].w;
                s2 += v[j].x * v[j].x + v[j].y * v[j].y + v[j].z * v[j].z + v[j].w * v[j].w;
            }
            s  += __shfl_xor(s, 1);  s  += __shfl_xor(s, 2);
            s2 += __shfl_xor(s2, 1); s2 += __shfl_xor(s2, 2);
            mean = s * (1.0f / D_);
            const float var = s2 * (1.0f / D_) - mean * mean;
            rstd = rsqrtf(var + 1e-5f);
        }
        ushort* dst = &sLN[prow * 264 + pq * 64];
#pragma unroll
        for (int j = 0; j < 16; ++j) {
            short4 o;
            if (LNMODE) {
                const int c = pq * 64 + j * 4;
                o.x = f2bf((v[j].x - mean) * rstd * lng[c + 0] + lnb[c + 0]);
                o.y = f2bf((v[j].y - mean) * rstd * lng[c + 1] + lnb[c + 1]);
                o.z = f2bf((v[j].z - mean) * rstd * lng[c + 2] + lnb[c + 2]);
                o.w = f2bf((v[j].w - mean) * rstd * lng[c + 3] + lnb[c + 3]);
            } else {
                o.x = f2bf(v[j].x); o.y = f2bf(v[j].y);
                o.z = f2bf(v[j].z); o.w = f2bf(v[j].w);
            }
            *reinterpret_cast<short4*>(dst + j * 4) = o;
        }
    }

    const int ra = (wr * 32 + nn) * 264, rb = ra + 16 * 264;
    const int rc = (wc * 32 + nn) * 64,  rd = rc + 16 * 64;
    const int m7 = nn & 7;

    int cur = 0;
    __syncthreads();   // sLN written by all; W buf0 landed (barrier drains vmcnt)
#pragma unroll
    for (int k0 = 0; k0 < 256; k0 += 64) {
        if (k0 + 64 < 256) {
            ushort* lW = ldsW + (cur ^ 1) * 4096;
            gload_lds16(Wp + k0 + 64,            lW);
            gload_lds16(Wp + k0 + 64 + 32 * 256, lW + 2048);
        }
        const ushort* w = sW + cur * 4096;
#pragma unroll
        for (int sk = 0; sk < 2; ++sk) {
            const int ac = k0 + sk * 32 + g * 8;
            bf16x8 a0 = *reinterpret_cast<const bf16x8*>(&sLN[ra + ac]);
            bf16x8 a1 = *reinterpret_cast<const bf16x8*>(&sLN[rb + ac]);
            const int sw = ((sk * 4 + g) ^ m7) << 3;
            bf16x8 w0 = *reinterpret_cast<const bf16x8*>(&w[rc + sw]);
            bf16x8 w1 = *reinterpret_cast<const bf16x8*>(&w[rd + sw]);
            acc[0][0] = __builtin_amdgcn_mfma_f32_16x16x32_bf16(a0, w0, acc[0][0], 0, 0, 0);
            acc[0][1] = __builtin_amdgcn_mfma_f32_16x16x32_bf16(a0, w1, acc[0][1], 0, 0, 0);
            acc[1][0] = __builtin_amdgcn_mfma_f32_16x16x32_bf16(a1, w0, acc[1][0], 0, 0, 0);
            acc[1][1] = __builtin_amdgcn_mfma_f32_16x16x32_bf16(a1, w1, acc[1][1], 0, 0, 0);
        }
        __syncthreads();
        cur ^= 1;
    }
}

// ---------------------------------------------------------------------------
// LN-fused GEMM + epilogue. LNMODE 0/1; EPI: 0 none, 1 exact GELU.
// OUTBF: 1 -> bf16 out, 0 -> fp32 out. K = 256.
// ---------------------------------------------------------------------------
template<int LNMODE, int EPI, int OUTBF>
__global__ __launch_bounds__(256) void gemm_ln(
    const float* __restrict__ Hin, const float* __restrict__ lng,
    const float* __restrict__ lnb, const ushort* __restrict__ Wt,
    const float* __restrict__ bias, void* __restrict__ Cout, int N)
{
    __shared__ __align__(16) ushort sLN[64 * 264];
    __shared__ __align__(16) ushort sW[2 * 4096];
    const int row0 = blockIdx.y * 64, col0 = blockIdx.x * 64;
    f32x4 acc[2][2] = {};
    gemm_core_ln<LNMODE>(Hin, lng, lnb, Wt, row0, col0, sLN, sW, acc);

    const int lane = threadIdx.x & 63;
    const int wid  = threadIdx.x >> 6;
    const int wr = wid >> 1, wc = wid & 1;
    const int g = lane >> 4, nn = lane & 15;
#pragma unroll
    for (int mi = 0; mi < 2; ++mi)
#pragma unroll
    for (int ni = 0; ni < 2; ++ni)
#pragma unroll
    for (int r = 0; r < 4; ++r) {
        const int m = row0 + wr * 32 + mi * 16 + g * 4 + r;
        const int c = col0 + wc * 32 + ni * 16 + nn;
        float v = acc[mi][ni][r] + bias[c];
        if (EPI == 1) v = 0.5f * v * (1.0f + erff(v * 0.70710678118654752f));
        if (OUTBF) ((ushort*)Cout)[(size_t)m * N + c] = (ushort)f2bf(v);
        else       ((float*)Cout)[(size_t)m * N + c] = v;
    }
}

// ---------------------------------------------------------------------------
// LN-fused QKV GEMM: grid.x = 12 (0-3 Q, 4-7 K, 8-11 V), grid.y = 64.
// Q,K -> bf16 row-major. V -> transposed Vt[b][h][d][l].
// ---------------------------------------------------------------------------
__global__ __launch_bounds__(256) void gemm_qkv_ln(
    const float* __restrict__ Hin, const float* __restrict__ lng,
    const float* __restrict__ lnb,
    const ushort* __restrict__ WqT, const ushort* __restrict__ WkT,
    const ushort* __restrict__ WvT,
    const float* __restrict__ bq, const float* __restrict__ bk,
    const float* __restrict__ bv,
    ushort* __restrict__ Qb, ushort* __restrict__ Kb, ushort* __restrict__ Vt)
{
    __shared__ __align__(16) ushort sLN[64 * 264];
    __shared__ __align__(16) ushort sW[2 * 4096];
    const int nb = blockIdx.x;
    const int wsel = nb >> 2;
    const int col0 = (nb & 3) * 64;
    const int row0 = blockIdx.y * 64;
    const ushort* Wt = (wsel == 0) ? WqT : (wsel == 1) ? WkT : WvT;
    const float* bias = (wsel == 0) ? bq : (wsel == 1) ? bk : bv;

    f32x4 acc[2][2] = {};
    gemm_core_ln<1>(Hin, lng, lnb, Wt, row0, col0, sLN, sW, acc);

    const int lane = threadIdx.x & 63;
    const int wid  = threadIdx.x >> 6;
    const int wr = wid >> 1, wc = wid & 1;
    const int g = lane >> 4, nn = lane & 15;
    ushort* QK = (wsel == 0) ? Qb : Kb;
#pragma unroll
    for (int mi = 0; mi < 2; ++mi)
#pragma unroll
    for (int ni = 0; ni < 2; ++ni)
#pragma unroll
    for (int r = 0; r < 4; ++r) {
        const int m = row0 + wr * 32 + mi * 16 + g * 4 + r;
        const int c = col0 + wc * 32 + ni * 16 + nn;
        const float v = acc[mi][ni][r] + bias[c];
        if (wsel < 2) {
            QK[(size_t)m * D_ + c] = (ushort)f2bf(v);
        } else {
            const int b = m >> 11, l = m & 2047;
            const int h = c >> 5,  d = c & 31;
            Vt[(size_t)((b * 8 + h) * 32 + d) * L_ + l] = (ushort)f2bf(v);
        }
    }
}

// ---------------------------------------------------------------------------
// bf16 A GEMM (async DMA both sides) + residual epilogue — for Wo and FF2.
// (round-6 core, unchanged: it passed)
// ---------------------------------------------------------------------------
__device__ __forceinline__ void gemm_core64(
    const ushort* __restrict__ A, const ushort* __restrict__ Wt, int K,
    int row0, int col0, ushort* sA, ushort* sW, f32x4 acc[2][2])
{
    const int tid  = threadIdx.x;
    const int lane = tid & 63;
    const int wid  = tid >> 6;
    const int wr = wid >> 1, wc = wid & 1;
    const int g = lane >> 4, nn = lane & 15;

    const int r0 = tid >> 3;
    const int sx = ((tid & 7) ^ (r0 & 7)) << 3;

    const ushort* Ap = &A[(size_t)(row0 + r0) * K + sx];
    const ushort* Wp = &Wt[(size_t)(col0 + r0) * K + sx];
    const size_t rstep = (size_t)32 * K;

    ushort* ldsA = sA + wid * 512;
    ushort* ldsW = sW + wid * 512;

    gload_lds16(Ap,         ldsA);
    gload_lds16(Ap + rstep, ldsA + 2048);
    gload_lds16(Wp,         ldsW);
    gload_lds16(Wp + rstep, ldsW + 2048);

    const int ra = (wr * 32 + nn) * 64, rb = ra + 16 * 64;
    const int rc = (wc * 32 + nn) * 64, rd = rc + 16 * 64;
    const int m7 = nn & 7;

    int cur = 0;
    __syncthreads();
    for (int k0 = 0; k0 < K; k0 += 64) {
        if (k0 + 64 < K) {
            ushort* lA = ldsA + (cur ^ 1) * 4096;
            ushort* lW = ldsW + (cur ^ 1) * 4096;
            gload_lds16(Ap + k0 + 64,         lA);
            gload_lds16(Ap + k0 + 64 + rstep, lA + 2048);
            gload_lds16(Wp + k0 + 64,         lW);
            gload_lds16(Wp + k0 + 64 + rstep, lW + 2048);
        }
        const ushort* a = sA + cur * 4096;
        const ushort* w = sW + cur * 4096;
#pragma unroll
        for (int sk = 0; sk < 2; ++sk) {
            const int sw = ((sk * 4 + g) ^ m7) << 3;
            bf16x8 a0 = *reinterpret_cast<const bf16x8*>(&a[ra + sw]);
            bf16x8 a1 = *reinterpret_cast<const bf16x8*>(&a[rb + sw]);
            bf16x8 w0 = *reinterpret_cast<const bf16x8*>(&w[rc + sw]);
            bf16x8 w1 = *reinterpret_cast<const bf16x8*>(&w[rd + sw]);
            acc[0][0] = __builtin_amdgcn_mfma_f32_16x16x32_bf16(a0, w0, acc[0][0], 0, 0, 0);
            acc[0][1] = __builtin_amdgcn_mfma_f32_16x16x32_bf16(a0, w1, acc[0][1], 0, 0, 0);
            acc[1][0] = __builtin_amdgcn_mfma_f32_16x16x32_bf16(a1, w0, acc[1][0], 0, 0, 0);
            acc[1][1] = __builtin_amdgcn_mfma_f32_16x16x32_bf16(a1, w1, acc[1][1], 0, 0, 0);
        }
        __syncthreads();
        cur ^= 1;
    }
}

__global__ __launch_bounds__(256) void gemm_res(
    const ushort* __restrict__ A, const ushort* __restrict__ Wt,
    const float* __restrict__ bias, float* __restrict__ C, int K)
{
    __shared__ __align__(16) ushort sA[2 * 4096];
    __shared__ __align__(16) ushort sW[2 * 4096];
    const int row0 = blockIdx.y * 64, col0 = blockIdx.x * 64;
    f32x4 acc[2][2] = {};
    gemm_core64(A, Wt, K, row0, col0, sA, sW, acc);

    const int lane = threadIdx.x & 63;
    const int wid  = threadIdx.x >> 6;
    const int wr = wid >> 1, wc = wid & 1;
    const int g = lane >> 4, nn = lane & 15;
#pragma unroll
    for (int mi = 0; mi < 2; ++mi)
#pragma unroll
    for (int ni = 0; ni < 2; ++ni)
#pragma unroll
    for (int r = 0; r < 4; ++r) {
        const int m = row0 + wr * 32 + mi * 16 + g * 4 + r;
        const int c = col0 + wc * 32 + ni * 16 + nn;
        C[(size_t)m * D_ + c] += acc[mi][ni][r] + bias[c];
    }
}

// ---------------------------------------------------------------------------
// MFMA evidence attention (round-6 body) + fused uncertainty finalize on the
// last layer (writes out_unc / out_abst directly).
// ---------------------------------------------------------------------------
__global__ __launch_bounds__(256) void attn_mfma(
    const ushort* __restrict__ Qb, const ushort* __restrict__ Kb,
    const ushort* __restrict__ Vt, ushort* __restrict__ O,
    float* __restrict__ unc, const float* __restrict__ ev_scale,
    const float* __restrict__ ev_bias, int layer,
    float* __restrict__ out_unc, float* __restrict__ out_abst)
{
    const int bh = blockIdx.y;
    const int b  = bh >> 3;
    const int h  = bh & 7;
    const int tid  = threadIdx.x;
    const int wv   = tid >> 6;
    const int lane = tid & 63;
    const int g = lane >> 4;
    const int n = lane & 15;
    const int q  = blockIdx.x * 64 + wv * 16 + n;
    const float scale = ev_scale[layer];
    const float cb    = 1.0f + ev_bias[layer];
    const float isq   = 0.17677669529663687f;   // 1/sqrt(32)

    __shared__ __align__(16) ushort sK[2][64][40];
    __shared__ __align__(16) ushort sV[2][32][72];

    const size_t qk0 = (size_t)b * L_ * D_ + h * HD_;

    bf16x8 qf;
    {
        const bf16x8 qr = *reinterpret_cast<const bf16x8*>(&Qb[qk0 + (size_t)q * D_ + g * 8]);
#pragma unroll
        for (int j = 0; j < 8; ++j) {
            const float qv = __builtin_bit_cast(float, ((unsigned)(unsigned short)qr[j]) << 16);
            qf[j] = f2bf(qv * isq);
        }
    }
    bf16x8 ones;
#pragma unroll
    for (int j = 0; j < 8; ++j) ones[j] = (short)0x3F80;

    const int krow = tid >> 2, kch = (tid & 3) * 8;
    const int vrow = tid >> 3, vch = (tid & 7) * 8;
    const ushort* ksrc = Kb + qk0 + (size_t)krow * D_ + kch;
    const ushort* vsrc = Vt + (size_t)((b * 8 + h) * 32 + vrow) * L_ + vch;

    f32x4 acc0 = {0.f, 0.f, 0.f, 0.f};
    f32x4 acc1 = {0.f, 0.f, 0.f, 0.f};
    f32x4 accS = {0.f, 0.f, 0.f, 0.f};
    const f32x4 zero = {0.f, 0.f, 0.f, 0.f};

    bf16x8 kreg = *reinterpret_cast<const bf16x8*>(ksrc);
    bf16x8 vreg = *reinterpret_cast<const bf16x8*>(vsrc);

    int cur = 0;
    for (int t = 0; t < L_; t += 64) {
        *reinterpret_cast<bf16x8*>(&sK[cur][krow][kch]) = kreg;
        *reinterpret_cast<bf16x8*>(&sV[cur][vrow][vch]) = vreg;
        if (t + 64 < L_) {
            kreg = *reinterpret_cast<const bf16x8*>(ksrc + (size_t)(t + 64) * D_);
            vreg = *reinterpret_cast<const bf16x8*>(vsrc + (t + 64));
        }
        __syncthreads();

#pragma unroll
        for (int tt = 0; tt < 64; tt += 32) {
            bf16x8 kf0 = *reinterpret_cast<const bf16x8*>(&sK[cur][tt + n][g * 8]);
            bf16x8 kf1 = *reinterpret_cast<const bf16x8*>(&sK[cur][tt + 16 + n][g * 8]);

            f32x4 s0 = __builtin_amdgcn_mfma_f32_16x16x32_bf16(kf0, qf, zero, 0, 0, 0);
            f32x4 s1 = __builtin_amdgcn_mfma_f32_16x16x32_bf16(kf1, qf, zero, 0, 0, 0);

            short4 va = *reinterpret_cast<const short4*>(&sV[cur][n][tt + g * 4]);
            short4 vb = *reinterpret_cast<const short4*>(&sV[cur][n][tt + 16 + g * 4]);
            short4 vc = *reinterpret_cast<const short4*>(&sV[cur][n + 16][tt + g * 4]);
            short4 vd = *reinterpret_cast<const short4*>(&sV[cur][n + 16][tt + 16 + g * 4]);
            bf16x8 vf0 = {va.x, va.y, va.z, va.w, vb.x, vb.y, vb.z, vb.w};
            bf16x8 vf1 = {vc.x, vc.y, vc.z, vc.w, vd.x, vd.y, vd.z, vd.w};

            bf16x8 pa;
#pragma unroll
            for (int r = 0; r < 4; ++r) pa[r]     = f2bf(fmaf(__expf(s0[r]), scale, cb));
#pragma unroll
            for (int r = 0; r < 4; ++r) pa[r + 4] = f2bf(fmaf(__expf(s1[r]), scale, cb));

            acc0 = __builtin_amdgcn_mfma_f32_16x16x32_bf16(vf0, pa, acc0, 0, 0, 0);
            acc1 = __builtin_amdgcn_mfma_f32_16x16x32_bf16(vf1, pa, acc1, 0, 0, 0);
            accS = __builtin_amdgcn_mfma_f32_16x16x32_bf16(ones, pa, accS, 0, 0, 0);
        }
        cur ^= 1;
    }

    const float inv = 1.0f / accS[0];

    ushort* op = &O[qk0 + (size_t)q * D_ + g * 4];
    short4 o0 = {f2bf(acc0[0] * inv), f2bf(acc0[1] * inv), f2bf(acc0[2] * inv), f2bf(acc0[3] * inv)};
    short4 o1 = {f2bf(acc1[0] * inv), f2bf(acc1[1] * inv), f2bf(acc1[2] * inv), f2bf(acc1[3] * inv)};
    *reinterpret_cast<short4*>(op)      = o0;
    *reinterpret_cast<short4*>(op + 16) = o1;

    if (g == 0) {
        const float u = (float)L_ * inv;
        const int uidx = bh * L_ + q;
        if (layer == 0) {
            unc[uidx] = u;                      // '=' : deterministic across replays
        } else if (layer < LY_ - 1) {
            unc[uidx] += u;
        } else {
            const float avg = (unc[uidx] + u) * 0.25f;
            out_unc[uidx]  = avg;
            out_abst[uidx] = (avg > 0.3f) ? 1.0f : 0.0f;
        }
    }
}

// ---------------------------------------------------------------------------
extern "C" void kernel_launch(void* const* d_in, const int* in_sizes, int n_in,
                              void* d_out, int out_size, void* d_ws, size_t ws_size,
                              hipStream_t stream)
{
    const float* x    = (const float*)d_in[0];
    const float* Win  = (const float*)d_in[1];
    const float* bin_ = (const float*)d_in[2];
    const float* Wq   = (const float*)d_in[3];
    const float* bq   = (const float*)d_in[4];
    const float* Wk   = (const float*)d_in[5];
    const float* bk   = (const float*)d_in[6];
    const float* Wv   = (const float*)d_in[7];
    const float* bv   = (const float*)d_in[8];
    const float* Wo   = (const float*)d_in[9];
    const float* bo   = (const float*)d_in[10];
    const float* evs  = (const float*)d_in[11];
    const float* evb  = (const float*)d_in[12];
    const float* W1   = (const float*)d_in[13];
    const float* b1   = (const float*)d_in[14];
    const float* W2   = (const float*)d_in[15];
    const float* b2   = (const float*)d_in[16];
    const float* n1g  = (const float*)d_in[17];
    const float* n1b  = (const float*)d_in[18];
    const float* n2g  = (const float*)d_in[19];
    const float* n2b  = (const float*)d_in[20];
    const float* fng  = (const float*)d_in[21];
    const float* fnb  = (const float*)d_in[22];
    const float* Wout = (const float*)d_in[23];
    const float* bout = (const float*)d_in[24];

    char* ws = (char*)d_ws;
    float*  h    = (float*) (ws);                  // 4 MB fp32 residual stream
    ushort* Qb   = (ushort*)(ws + (6  << 20));     // 2 MB
    ushort* Kb   = (ushort*)(ws + (8  << 20));     // 2 MB
    ushort* Vt   = (ushort*)(ws + (10 << 20));     // 2 MB (transposed V)
    ushort* Ob   = (ushort*)(ws + (12 << 20));     // 2 MB (attn out)
    ushort* ffb  = (ushort*)(ws + (4  << 20));     // 8 MB, overlays Qb..Ob (dead by FF1)
    float*  unc  = (float*) (ws + (14 << 20));     // 128 KB
    ushort* T    = (ushort*)(ws + (15 << 20));     // 6.55 MB transposed bf16 weights

    ushort* winT  = T;
    ushort* woutT = T + 65536 * 17 + 2097152;

    float* out_main = (float*)d_out;
    float* out_unc  = out_main + M_ * D_;
    float* out_abst = out_unc + B_ * H_ * L_;

    const dim3 blk(256);
    const dim3 g256(4, 64);     // N=256 GEMMs
    const dim3 g1024(16, 64);   // N=1024 GEMM
    const dim3 gqkv(12, 64);
    const dim3 gattn(L_ / 64, B_ * H_);

    transpose_weights<<<3200, blk, 0, stream>>>(Win, Wq, Wk, Wv, Wo, W1, W2, Wout, T);
    // h = x @ Win + bin   (convert-only prologue)
    gemm_ln<0, 0, 0><<<g256, blk, 0, stream>>>(x, nullptr, nullptr, winT, bin_, h, D_);

    for (int i = 0; i < LY_; ++i) {
        ushort* wqT = T + 65536 * (1 + i);
        ushort* wkT = T + 65536 * (5 + i);
        ushort* wvT = T + 65536 * (9 + i);
        ushort* woT = T + 65536 * (13 + i);
        ushort* w1T = T + 65536 * 17 + i * 262144;
        ushort* w2T = T + 65536 * 17 + 1048576 + i * 262144;

        gemm_qkv_ln<<<gqkv, blk, 0, stream>>>(h, n1g + i * D_, n1b + i * D_,
                                              wqT, wkT, wvT,
                                              bq + i * D_, bk + i * D_, bv + i * D_,
                                              Qb, Kb, Vt);
        attn_mfma<<<gattn, blk, 0, stream>>>(Qb, Kb, Vt, Ob, unc, evs, evb, i,
                                             out_unc, out_abst);
        gemm_res<<<g256, blk, 0, stream>>>(Ob, woT, bo + i * D_, h, D_);
        gemm_ln<1, 1, 1><<<g1024, blk, 0, stream>>>(h, n2g + i * D_, n2b + i * D_,
                                                    w1T, b1 + i * F_, ffb, F_);
        gemm_res<<<g256, blk, 0, stream>>>(ffb, w2T, b2 + i * D_, h, F_);
    }

    gemm_ln<1, 0, 0><<<g256, blk, 0, stream>>>(h, fng, fnb, woutT, bout, out_main, D_);
}

// Round 9
// 322.700 us; speedup vs baseline: 1.3327x; 1.3327x over previous
//
#include <hip/hip_runtime.h>
#include <hip/hip_bf16.h>
#include <math.h>

#define B_  2
#define L_  2048
#define D_  256
#define H_  8
#define HD_ 32
#define F_  1024
#define LY_ 4
#define M_  (B_*L_)

typedef __attribute__((ext_vector_type(8))) short bf16x8;   // 8 bf16 in 4 VGPRs
typedef __attribute__((ext_vector_type(4))) float f32x4;

static __device__ __forceinline__ short f2bf(float f) {
    return __builtin_bit_cast(short, __float2bfloat16(f));
}

static __device__ __forceinline__ void gload_lds16(const ushort* g, ushort* l) {
    __builtin_amdgcn_global_load_lds(
        (const __attribute__((address_space(1))) void*)g,
        (__attribute__((address_space(3))) void*)l, 16, 0, 0);
}

// ---------------------------------------------------------------------------
// Weight transpose + fp32->bf16:  W[K][N] -> Wt[N][K] bf16  (unchanged)
// ---------------------------------------------------------------------------
__global__ __launch_bounds__(256) void transpose_weights(
    const float* __restrict__ Win, const float* __restrict__ Wq,
    const float* __restrict__ Wk,  const float* __restrict__ Wv,
    const float* __restrict__ Wo,  const float* __restrict__ W1,
    const float* __restrict__ W2,  const float* __restrict__ Wout,
    ushort* __restrict__ T)
{
    const int bid = blockIdx.x;
    const float* src; ushort* dst; int K, N, tt;
    if (bid < 64)        { src = Win; dst = T; K = 256; N = 256; tt = bid; }
    else if (bid < 1088) {
        int i = bid - 64; int which = i >> 8; int l = (i >> 6) & 3; tt = i & 63;
        K = 256; N = 256;
        const float* s4[4] = {Wq, Wk, Wv, Wo};
        src = s4[which] + l * 65536;
        dst = T + 65536 * (1 + which * 4 + l);
    } else if (bid < 2112) {
        int i = bid - 1088; int l = i >> 8; tt = i & 255; K = 256; N = 1024;
        src = W1 + l * 262144; dst = T + 65536 * 17 + l * 262144;
    } else if (bid < 3136) {
        int i = bid - 2112; int l = i >> 8; tt = i & 255; K = 1024; N = 256;
        src = W2 + l * 262144; dst = T + 65536 * 17 + 1048576 + l * 262144;
    } else {
        src = Wout; dst = T + 65536 * 17 + 2097152; K = 256; N = 256; tt = bid - 3136;
    }
    const int ntn = N >> 5;
    const int tk = tt / ntn, tn = tt % ntn;
    __shared__ float ld[32][33];
    const int t = threadIdx.x;
    const int r = t >> 3, c4 = (t & 7) * 4;
    float4 v = *reinterpret_cast<const float4*>(&src[(size_t)(tk * 32 + r) * N + tn * 32 + c4]);
    ld[r][c4 + 0] = v.x; ld[r][c4 + 1] = v.y; ld[r][c4 + 2] = v.z; ld[r][c4 + 3] = v.w;
    __syncthreads();
    short4 o;
    o.x = f2bf(ld[c4 + 0][r]);
    o.y = f2bf(ld[c4 + 1][r]);
    o.z = f2bf(ld[c4 + 2][r]);
    o.w = f2bf(ld[c4 + 3][r]);
    *reinterpret_cast<short4*>(&dst[(size_t)(tn * 32 + r) * K + tk * 32 + c4]) = o;
}

// ---------------------------------------------------------------------------
// Self-contained LN-fused consumer core (K=256): coalesced fp32 A-tile load;
// per-row LN stats via in-wave 64-lane butterfly (each wave holds complete
// rows 4j+wid across its lanes) — NO cross-kernel stats; bf16 A-tile in LDS
// [64][264]; W streamed via async global_load_lds, double-buffered.
// LNM: 0 = convert-only, 1 = LayerNorm.
// ---------------------------------------------------------------------------
template<int LNM>
__device__ __forceinline__ void core_f(
    const float* __restrict__ Hin, const float* __restrict__ lng,
    const float* __restrict__ lnb, const ushort* __restrict__ Wt,
    int row0, int col0, ushort* sLN, ushort* sW, f32x4 acc[2][2])
{
    const int tid  = threadIdx.x;
    const int lane = tid & 63;
    const int wid  = tid >> 6;
    const int wr = wid >> 1, wc = wid & 1;
    const int g = lane >> 4, nn = lane & 15;

    // W DMA for k0=0 (in flight across the prologue)
    const int r0 = tid >> 3;
    const int sx = ((tid & 7) ^ (r0 & 7)) << 3;
    const ushort* Wp = &Wt[(size_t)(col0 + r0) * 256 + sx];
    ushort* ldsW = sW + wid * 512;
    gload_lds16(Wp,            ldsW);
    gload_lds16(Wp + 32 * 256, ldsW + 2048);

    // A-tile: fully coalesced fp32 loads; lane holds float4-col `lane` of
    // rows {4j + wid}.
    const float4* hp = reinterpret_cast<const float4*>(Hin + (size_t)row0 * D_);
    float4 av[16];
#pragma unroll
    for (int j = 0; j < 16; ++j) av[j] = hp[j * 256 + tid];

    float4 g4, b4;
    if (LNM) {
        g4 = reinterpret_cast<const float4*>(lng)[lane];
        b4 = reinterpret_cast<const float4*>(lnb)[lane];
    }
#pragma unroll
    for (int j = 0; j < 16; ++j) {
        const float4 v = av[j];
        short4 o;
        if (LNM) {
            float s  = v.x + v.y + v.z + v.w;
            float s2 = v.x * v.x + v.y * v.y + v.z * v.z + v.w * v.w;
            s  += __shfl_xor(s, 1);  s  += __shfl_xor(s, 2);  s  += __shfl_xor(s, 4);
            s  += __shfl_xor(s, 8);  s  += __shfl_xor(s, 16); s  += __shfl_xor(s, 32);
            s2 += __shfl_xor(s2, 1); s2 += __shfl_xor(s2, 2); s2 += __shfl_xor(s2, 4);
            s2 += __shfl_xor(s2, 8); s2 += __shfl_xor(s2, 16); s2 += __shfl_xor(s2, 32);
            const float mean = s * (1.0f / D_);
            const float var  = s2 * (1.0f / D_) - mean * mean;
            const float rstd = rsqrtf(var + 1e-5f);
            o.x = f2bf((v.x - mean) * rstd * g4.x + b4.x);
            o.y = f2bf((v.y - mean) * rstd * g4.y + b4.y);
            o.z = f2bf((v.z - mean) * rstd * g4.z + b4.z);
            o.w = f2bf((v.w - mean) * rstd * g4.w + b4.w);
        } else {
            o.x = f2bf(v.x); o.y = f2bf(v.y); o.z = f2bf(v.z); o.w = f2bf(v.w);
        }
        *reinterpret_cast<short4*>(&sLN[(j * 4 + wid) * 264 + lane * 4]) = o;
    }
    __syncthreads();   // sLN visible; W buf0 landed (barrier drains vmcnt)

    const int ra = (wr * 32 + nn) * 264, rb = ra + 16 * 264;
    const int rc = (wc * 32 + nn) * 64,  rd = rc + 16 * 64;
    const int m7 = nn & 7;

    int cur = 0;
#pragma unroll
    for (int k0 = 0; k0 < 256; k0 += 64) {
        if (k0 + 64 < 256) {
            ushort* lW = ldsW + (cur ^ 1) * 4096;
            gload_lds16(Wp + k0 + 64,            lW);
            gload_lds16(Wp + k0 + 64 + 32 * 256, lW + 2048);
        }
        const ushort* w = sW + cur * 4096;
#pragma unroll
        for (int sk = 0; sk < 2; ++sk) {
            const int ac = k0 + sk * 32 + g * 8;
            bf16x8 a0 = *reinterpret_cast<const bf16x8*>(&sLN[ra + ac]);
            bf16x8 a1 = *reinterpret_cast<const bf16x8*>(&sLN[rb + ac]);
            const int sw = ((sk * 4 + g) ^ m7) << 3;
            bf16x8 w0 = *reinterpret_cast<const bf16x8*>(&w[rc + sw]);
            bf16x8 w1 = *reinterpret_cast<const bf16x8*>(&w[rd + sw]);
            acc[0][0] = __builtin_amdgcn_mfma_f32_16x16x32_bf16(a0, w0, acc[0][0], 0, 0, 0);
            acc[0][1] = __builtin_amdgcn_mfma_f32_16x16x32_bf16(a0, w1, acc[0][1], 0, 0, 0);
            acc[1][0] = __builtin_amdgcn_mfma_f32_16x16x32_bf16(a1, w0, acc[1][0], 0, 0, 0);
            acc[1][1] = __builtin_amdgcn_mfma_f32_16x16x32_bf16(a1, w1, acc[1][1], 0, 0, 0);
        }
        __syncthreads();
        cur ^= 1;
    }
}

// ---------------------------------------------------------------------------
// LN-fused GEMM + epilogue. LNM 0/1; EPI: 0 none, 1 exact GELU; OUTBF.
// ---------------------------------------------------------------------------
template<int LNM, int EPI, int OUTBF>
__global__ __launch_bounds__(256) void gemm_fused(
    const float* __restrict__ Hin, const float* __restrict__ lng,
    const float* __restrict__ lnb, const ushort* __restrict__ Wt,
    const float* __restrict__ bias, void* __restrict__ Cout, int N)
{
    __shared__ __align__(16) ushort sLN[64 * 264];
    __shared__ __align__(16) ushort sW[2 * 4096];
    const int row0 = blockIdx.y * 64, col0 = blockIdx.x * 64;
    f32x4 acc[2][2] = {};
    core_f<LNM>(Hin, lng, lnb, Wt, row0, col0, sLN, sW, acc);

    const int lane = threadIdx.x & 63;
    const int wid  = threadIdx.x >> 6;
    const int wr = wid >> 1, wc = wid & 1;
    const int g = lane >> 4, nn = lane & 15;
#pragma unroll
    for (int mi = 0; mi < 2; ++mi)
#pragma unroll
    for (int ni = 0; ni < 2; ++ni)
#pragma unroll
    for (int r = 0; r < 4; ++r) {
        const int m = row0 + wr * 32 + mi * 16 + g * 4 + r;
        const int c = col0 + wc * 32 + ni * 16 + nn;
        float v = acc[mi][ni][r] + bias[c];
        if (EPI == 1) v = 0.5f * v * (1.0f + erff(v * 0.70710678118654752f));
        if (OUTBF) ((ushort*)Cout)[(size_t)m * N + c] = (ushort)f2bf(v);
        else       ((float*)Cout)[(size_t)m * N + c] = v;
    }
}

// ---------------------------------------------------------------------------
// LN-fused QKV GEMM: grid.x = 12 (0-3 Q, 4-7 K, 8-11 V), grid.y = 64.
// Q,K -> bf16 row-major. V -> transposed Vt[b][h][d][l].
// ---------------------------------------------------------------------------
__global__ __launch_bounds__(256) void gemm_qkv_f(
    const float* __restrict__ Hin, const float* __restrict__ lng,
    const float* __restrict__ lnb,
    const ushort* __restrict__ WqT, const ushort* __restrict__ WkT,
    const ushort* __restrict__ WvT,
    const float* __restrict__ bq, const float* __restrict__ bk,
    const float* __restrict__ bv,
    ushort* __restrict__ Qb, ushort* __restrict__ Kb, ushort* __restrict__ Vt)
{
    __shared__ __align__(16) ushort sLN[64 * 264];
    __shared__ __align__(16) ushort sW[2 * 4096];
    const int nb = blockIdx.x;
    const int wsel = nb >> 2;
    const int col0 = (nb & 3) * 64;
    const int row0 = blockIdx.y * 64;
    const ushort* Wt = (wsel == 0) ? WqT : (wsel == 1) ? WkT : WvT;
    const float* bias = (wsel == 0) ? bq : (wsel == 1) ? bk : bv;

    f32x4 acc[2][2] = {};
    core_f<1>(Hin, lng, lnb, Wt, row0, col0, sLN, sW, acc);

    const int lane = threadIdx.x & 63;
    const int wid  = threadIdx.x >> 6;
    const int wr = wid >> 1, wc = wid & 1;
    const int g = lane >> 4, nn = lane & 15;
    ushort* QK = (wsel == 0) ? Qb : Kb;
#pragma unroll
    for (int mi = 0; mi < 2; ++mi)
#pragma unroll
    for (int ni = 0; ni < 2; ++ni)
#pragma unroll
    for (int r = 0; r < 4; ++r) {
        const int m = row0 + wr * 32 + mi * 16 + g * 4 + r;
        const int c = col0 + wc * 32 + ni * 16 + nn;
        const float v = acc[mi][ni][r] + bias[c];
        if (wsel < 2) {
            QK[(size_t)m * D_ + c] = (ushort)f2bf(v);
        } else {
            const int b = m >> 11, l = m & 2047;
            const int h = c >> 5,  d = c & 31;
            Vt[(size_t)((b * 8 + h) * 32 + d) * L_ + l] = (ushort)f2bf(v);
        }
    }
}

// ---------------------------------------------------------------------------
// bf16-A GEMM (round-6 verified core) + residual epilogue. Wo / FF2.
// ---------------------------------------------------------------------------
__device__ __forceinline__ void gemm_core64(
    const ushort* __restrict__ A, const ushort* __restrict__ Wt, int K,
    int row0, int col0, ushort* sA, ushort* sW, f32x4 acc[2][2])
{
    const int tid  = threadIdx.x;
    const int lane = tid & 63;
    const int wid  = tid >> 6;
    const int wr = wid >> 1, wc = wid & 1;
    const int g = lane >> 4, nn = lane & 15;

    const int r0 = tid >> 3;
    const int sx = ((tid & 7) ^ (r0 & 7)) << 3;

    const ushort* Ap = &A[(size_t)(row0 + r0) * K + sx];
    const ushort* Wp = &Wt[(size_t)(col0 + r0) * K + sx];
    const size_t rstep = (size_t)32 * K;

    ushort* ldsA = sA + wid * 512;
    ushort* ldsW = sW + wid * 512;

    gload_lds16(Ap,         ldsA);
    gload_lds16(Ap + rstep, ldsA + 2048);
    gload_lds16(Wp,         ldsW);
    gload_lds16(Wp + rstep, ldsW + 2048);

    const int ra = (wr * 32 + nn) * 64, rb = ra + 16 * 64;
    const int rc = (wc * 32 + nn) * 64, rd = rc + 16 * 64;
    const int m7 = nn & 7;

    int cur = 0;
    __syncthreads();
    for (int k0 = 0; k0 < K; k0 += 64) {
        if (k0 + 64 < K) {
            ushort* lA = ldsA + (cur ^ 1) * 4096;
            ushort* lW = ldsW + (cur ^ 1) * 4096;
            gload_lds16(Ap + k0 + 64,         lA);
            gload_lds16(Ap + k0 + 64 + rstep, lA + 2048);
            gload_lds16(Wp + k0 + 64,         lW);
            gload_lds16(Wp + k0 + 64 + rstep, lW + 2048);
        }
        const ushort* a = sA + cur * 4096;
        const ushort* w = sW + cur * 4096;
#pragma unroll
        for (int sk = 0; sk < 2; ++sk) {
            const int sw = ((sk * 4 + g) ^ m7) << 3;
            bf16x8 a0 = *reinterpret_cast<const bf16x8*>(&a[ra + sw]);
            bf16x8 a1 = *reinterpret_cast<const bf16x8*>(&a[rb + sw]);
            bf16x8 w0 = *reinterpret_cast<const bf16x8*>(&w[rc + sw]);
            bf16x8 w1 = *reinterpret_cast<const bf16x8*>(&w[rd + sw]);
            acc[0][0] = __builtin_amdgcn_mfma_f32_16x16x32_bf16(a0, w0, acc[0][0], 0, 0, 0);
            acc[0][1] = __builtin_amdgcn_mfma_f32_16x16x32_bf16(a0, w1, acc[0][1], 0, 0, 0);
            acc[1][0] = __builtin_amdgcn_mfma_f32_16x16x32_bf16(a1, w0, acc[1][0], 0, 0, 0);
            acc[1][1] = __builtin_amdgcn_mfma_f32_16x16x32_bf16(a1, w1, acc[1][1], 0, 0, 0);
        }
        __syncthreads();
        cur ^= 1;
    }
}

__global__ __launch_bounds__(256) void gemm_res(
    const ushort* __restrict__ A, const ushort* __restrict__ Wt,
    const float* __restrict__ bias, float* __restrict__ C, int K)
{
    __shared__ __align__(16) ushort sA[2 * 4096];
    __shared__ __align__(16) ushort sW[2 * 4096];
    const int row0 = blockIdx.y * 64, col0 = blockIdx.x * 64;
    f32x4 acc[2][2] = {};
    gemm_core64(A, Wt, K, row0, col0, sA, sW, acc);

    const int lane = threadIdx.x & 63;
    const int wid  = threadIdx.x >> 6;
    const int wr = wid >> 1, wc = wid & 1;
    const int g = lane >> 4, nn = lane & 15;
#pragma unroll
    for (int mi = 0; mi < 2; ++mi)
#pragma unroll
    for (int ni = 0; ni < 2; ++ni)
#pragma unroll
    for (int r = 0; r < 4; ++r) {
        const int m = row0 + wr * 32 + mi * 16 + g * 4 + r;
        const int c = col0 + wc * 32 + ni * 16 + nn;
        C[(size_t)m * D_ + c] += acc[mi][ni][r] + bias[c];
    }
}

// ---------------------------------------------------------------------------
// MFMA evidence attention (round-7 verified) + fused uncertainty finalize.
// ---------------------------------------------------------------------------
__global__ __launch_bounds__(256) void attn_mfma(
    const ushort* __restrict__ Qb, const ushort* __restrict__ Kb,
    const ushort* __restrict__ Vt, ushort* __restrict__ O,
    float* __restrict__ unc, const float* __restrict__ ev_scale,
    const float* __restrict__ ev_bias, int layer,
    float* __restrict__ out_unc, float* __restrict__ out_abst)
{
    const int bh = blockIdx.y;
    const int b  = bh >> 3;
    const int h  = bh & 7;
    const int tid  = threadIdx.x;
    const int wv   = tid >> 6;
    const int lane = tid & 63;
    const int g = lane >> 4;
    const int n = lane & 15;
    const int q  = blockIdx.x * 64 + wv * 16 + n;
    const float scale = ev_scale[layer];
    const float cb    = 1.0f + ev_bias[layer];
    const float isq   = 0.17677669529663687f;   // 1/sqrt(32)

    __shared__ __align__(16) ushort sK[2][64][40];
    __shared__ __align__(16) ushort sV[2][32][72];

    const size_t qk0 = (size_t)b * L_ * D_ + h * HD_;

    bf16x8 qf;
    {
        const bf16x8 qr = *reinterpret_cast<const bf16x8*>(&Qb[qk0 + (size_t)q * D_ + g * 8]);
#pragma unroll
        for (int j = 0; j < 8; ++j) {
            const float qv = __builtin_bit_cast(float, ((unsigned)(unsigned short)qr[j]) << 16);
            qf[j] = f2bf(qv * isq);
        }
    }
    bf16x8 ones;
#pragma unroll
    for (int j = 0; j < 8; ++j) ones[j] = (short)0x3F80;

    const int krow = tid >> 2, kch = (tid & 3) * 8;
    const int vrow = tid >> 3, vch = (tid & 7) * 8;
    const ushort* ksrc = Kb + qk0 + (size_t)krow * D_ + kch;
    const ushort* vsrc = Vt + (size_t)((b * 8 + h) * 32 + vrow) * L_ + vch;

    f32x4 acc0 = {0.f, 0.f, 0.f, 0.f};
    f32x4 acc1 = {0.f, 0.f, 0.f, 0.f};
    f32x4 accS = {0.f, 0.f, 0.f, 0.f};
    const f32x4 zero = {0.f, 0.f, 0.f, 0.f};

    bf16x8 kreg = *reinterpret_cast<const bf16x8*>(ksrc);
    bf16x8 vreg = *reinterpret_cast<const bf16x8*>(vsrc);

    int cur = 0;
    for (int t = 0; t < L_; t += 64) {
        *reinterpret_cast<bf16x8*>(&sK[cur][krow][kch]) = kreg;
        *reinterpret_cast<bf16x8*>(&sV[cur][vrow][vch]) = vreg;
        if (t + 64 < L_) {
            kreg = *reinterpret_cast<const bf16x8*>(ksrc + (size_t)(t + 64) * D_);
            vreg = *reinterpret_cast<const bf16x8*>(vsrc + (t + 64));
        }
        __syncthreads();

#pragma unroll
        for (int tt = 0; tt < 64; tt += 32) {
            bf16x8 kf0 = *reinterpret_cast<const bf16x8*>(&sK[cur][tt + n][g * 8]);
            bf16x8 kf1 = *reinterpret_cast<const bf16x8*>(&sK[cur][tt + 16 + n][g * 8]);

            f32x4 s0 = __builtin_amdgcn_mfma_f32_16x16x32_bf16(kf0, qf, zero, 0, 0, 0);
            f32x4 s1 = __builtin_amdgcn_mfma_f32_16x16x32_bf16(kf1, qf, zero, 0, 0, 0);

            short4 va = *reinterpret_cast<const short4*>(&sV[cur][n][tt + g * 4]);
            short4 vb = *reinterpret_cast<const short4*>(&sV[cur][n][tt + 16 + g * 4]);
            short4 vc = *reinterpret_cast<const short4*>(&sV[cur][n + 16][tt + g * 4]);
            short4 vd = *reinterpret_cast<const short4*>(&sV[cur][n + 16][tt + 16 + g * 4]);
            bf16x8 vf0 = {va.x, va.y, va.z, va.w, vb.x, vb.y, vb.z, vb.w};
            bf16x8 vf1 = {vc.x, vc.y, vc.z, vc.w, vd.x, vd.y, vd.z, vd.w};

            bf16x8 pa;
#pragma unroll
            for (int r = 0; r < 4; ++r) pa[r]     = f2bf(fmaf(__expf(s0[r]), scale, cb));
#pragma unroll
            for (int r = 0; r < 4; ++r) pa[r + 4] = f2bf(fmaf(__expf(s1[r]), scale, cb));

            acc0 = __builtin_amdgcn_mfma_f32_16x16x32_bf16(vf0, pa, acc0, 0, 0, 0);
            acc1 = __builtin_amdgcn_mfma_f32_16x16x32_bf16(vf1, pa, acc1, 0, 0, 0);
            accS = __builtin_amdgcn_mfma_f32_16x16x32_bf16(ones, pa, accS, 0, 0, 0);
        }
        cur ^= 1;
    }

    const float inv = 1.0f / accS[0];

    ushort* op = &O[qk0 + (size_t)q * D_ + g * 4];
    short4 o0 = {f2bf(acc0[0] * inv), f2bf(acc0[1] * inv), f2bf(acc0[2] * inv), f2bf(acc0[3] * inv)};
    short4 o1 = {f2bf(acc1[0] * inv), f2bf(acc1[1] * inv), f2bf(acc1[2] * inv), f2bf(acc1[3] * inv)};
    *reinterpret_cast<short4*>(op)      = o0;
    *reinterpret_cast<short4*>(op + 16) = o1;

    if (g == 0) {
        const float u = (float)L_ * inv;
        const int uidx = bh * L_ + q;
        if (layer == 0) {
            unc[uidx] = u;                      // '=' : deterministic across replays
        } else if (layer < LY_ - 1) {
            unc[uidx] += u;
        } else {
            const float avg = (unc[uidx] + u) * 0.25f;
            out_unc[uidx]  = avg;
            out_abst[uidx] = (avg > 0.3f) ? 1.0f : 0.0f;
        }
    }
}

// ---------------------------------------------------------------------------
extern "C" void kernel_launch(void* const* d_in, const int* in_sizes, int n_in,
                              void* d_out, int out_size, void* d_ws, size_t ws_size,
                              hipStream_t stream)
{
    const float* x    = (const float*)d_in[0];
    const float* Win  = (const float*)d_in[1];
    const float* bin_ = (const float*)d_in[2];
    const float* Wq   = (const float*)d_in[3];
    const float* bq   = (const float*)d_in[4];
    const float* Wk   = (const float*)d_in[5];
    const float* bk   = (const float*)d_in[6];
    const float* Wv   = (const float*)d_in[7];
    const float* bv   = (const float*)d_in[8];
    const float* Wo   = (const float*)d_in[9];
    const float* bo   = (const float*)d_in[10];
    const float* evs  = (const float*)d_in[11];
    const float* evb  = (const float*)d_in[12];
    const float* W1   = (const float*)d_in[13];
    const float* b1   = (const float*)d_in[14];
    const float* W2   = (const float*)d_in[15];
    const float* b2   = (const float*)d_in[16];
    const float* n1g  = (const float*)d_in[17];
    const float* n1b  = (const float*)d_in[18];
    const float* n2g  = (const float*)d_in[19];
    const float* n2b  = (const float*)d_in[20];
    const float* fng  = (const float*)d_in[21];
    const float* fnb  = (const float*)d_in[22];
    const float* Wout = (const float*)d_in[23];
    const float* bout = (const float*)d_in[24];

    char* ws = (char*)d_ws;
    float*  h    = (float*) (ws);                  // 4 MB fp32 residual stream
    ushort* Qb   = (ushort*)(ws + (6  << 20));     // 2 MB
    ushort* Kb   = (ushort*)(ws + (8  << 20));     // 2 MB
    ushort* Vt   = (ushort*)(ws + (10 << 20));     // 2 MB (transposed V)
    ushort* Ob   = (ushort*)(ws + (12 << 20));     // 2 MB (attn out)
    ushort* ffb  = (ushort*)(ws + (4  << 20));     // 8 MB, overlays Qb..Vt (dead by FF1)
    float*  unc  = (float*) (ws + (14 << 20));     // 128 KB
    ushort* T    = (ushort*)(ws + (15 << 20));     // 6.55 MB bf16 weights

    ushort* winT  = T;
    ushort* woutT = T + 65536 * 17 + 2097152;

    float* out_main = (float*)d_out;
    float* out_unc  = out_main + M_ * D_;
    float* out_abst = out_unc + B_ * H_ * L_;

    const dim3 blk(256);
    const dim3 g256(4, 64);     // N=256 GEMMs
    const dim3 g1024(16, 64);   // N=1024 GEMM
    const dim3 gqkv(12, 64);
    const dim3 gattn(L_ / 64, B_ * H_);

    transpose_weights<<<3200, blk, 0, stream>>>(Win, Wq, Wk, Wv, Wo, W1, W2, Wout, T);
    // h = x @ Win + bin  (convert-only A-prologue; replaces f32_to_bf16 + gemm)
    gemm_fused<0, 0, 0><<<g256, blk, 0, stream>>>(x, nullptr, nullptr, winT, bin_, h, D_);

    for (int i = 0; i < LY_; ++i) {
        ushort* wqT = T + 65536 * (1 + i);
        ushort* wkT = T + 65536 * (5 + i);
        ushort* wvT = T + 65536 * (9 + i);
        ushort* woT = T + 65536 * (13 + i);
        ushort* w1T = T + 65536 * 17 + i * 262144;
        ushort* w2T = T + 65536 * 17 + 1048576 + i * 262144;

        gemm_qkv_f<<<gqkv, blk, 0, stream>>>(h, n1g + i * D_, n1b + i * D_,
                                             wqT, wkT, wvT,
                                             bq + i * D_, bk + i * D_, bv + i * D_,
                                             Qb, Kb, Vt);
        attn_mfma<<<gattn, blk, 0, stream>>>(Qb, Kb, Vt, Ob, unc, evs, evb, i,
                                             out_unc, out_abst);
        gemm_res<<<g256, blk, 0, stream>>>(Ob, woT, bo + i * D_, h, D_);
        gemm_fused<1, 1, 1><<<g1024, blk, 0, stream>>>(h, n2g + i * D_, n2b + i * D_,
                                                       w1T, b1 + i * F_, ffb, F_);
        gemm_res<<<g256, blk, 0, stream>>>(ffb, w2T, b2 + i * D_, h, F_);
    }

    gemm_fused<1, 0, 0><<<g256, blk, 0, stream>>>(h, fng, fnb, woutT, bout, out_main, D_);
}